// Round 2
// baseline (3782.964 us; speedup 1.0000x reference)
//
#include <hip/hip_runtime.h>
#include <math.h>

#define DT_C 0.042f
#define Bn 128
#define Tn 1024
#define In 64
#define Hn 512

#define CL 8    // WGs per cluster (k-split factor)
#define NC 32   // clusters
#define BB 4    // batches per cluster
#define KS 64   // k-rows (and owned cols) per WG
#define FLAG_STRIDE 16  // uints (64 B) per flag

// ---------------------------------------------------------------------------
// Kernel A: u[b,t,h] = bias[h] + sum_i x[b,t,i] * x2h[i,h]  (in-place in d_out)
// ---------------------------------------------------------------------------
#define ROWS_A 256
__global__ __launch_bounds__(512) void ron_proj_kernel(
    const float* __restrict__ x, const float* __restrict__ x2h,
    const float* __restrict__ bias, float* __restrict__ u)
{
    __shared__ float xs[8 * In];
    const int h = threadIdx.x;
    const long row0 = (long)blockIdx.x * ROWS_A;

    float w[In];
    #pragma unroll
    for (int i = 0; i < In; ++i) w[i] = x2h[i * Hn + h];
    const float bh = bias[h];

    for (int r8 = 0; r8 < ROWS_A; r8 += 8) {
        __syncthreads();
        xs[h] = x[(row0 + r8) * In + h];
        __syncthreads();
        float acc[8];
        #pragma unroll
        for (int r = 0; r < 8; ++r) acc[r] = bh;
        #pragma unroll
        for (int i = 0; i < In; ++i) {
            #pragma unroll
            for (int r = 0; r < 8; ++r)
                acc[r] = fmaf(xs[r * In + i], w[i], acc[r]);
        }
        #pragma unroll
        for (int r = 0; r < 8; ++r)
            u[(row0 + r8 + r) * Hn + h] = acc[r];
    }
}

// ---------------------------------------------------------------------------
// Kernel B: k-split cluster scan. 256 WGs = 32 clusters x 8 WGs.
// WG j of cluster c: holds h2h rows [64j,64j+64) in REGISTERS (64 f32/thread),
// owns hy/hz columns [64j,64j+64) for the cluster's 4 batches.
// Per step: partial_j[bb, 0..511] = hy_own[bb,:] @ Wreg  (full k-slice in-thread),
// exchange column-chunks with the 7 mates via agent-scope stores + flags,
// sum 8 partials for own columns, tanh-update, write hy to out + LDS.
//
// Sync protocol is RELAXED-only by design (see R1: release/acquire cache
// maintenance cost 2.7x):
//  - all inter-WG data (chunks, flags) moves via agent-scope ATOMIC ops;
//  - producer ordering: chunk stores -> __syncthreads (drains vmcnt(0)) -> flag;
//  - consumer ordering: flag poll -> (control dep, in-order issue) -> gather.
// Cross-step safety: flag t+2 is stored after B1(t+1), which is after B3(t),
// which is after gather(t) — so parity buffers are never overwritten early.
//
// w_r[] is PINNED into VGPRs with per-element asm (R2): without it the
// allocator remats the h2h loads into the t-loop (VGPR_Count=56 observed),
// re-loading 64 weights/thread/step from L2 on the critical path.
// ---------------------------------------------------------------------------
__global__ __launch_bounds__(512, 2) void ron_scan_kernel(
    const float* __restrict__ h2h,
    const float* __restrict__ gamma,
    const float* __restrict__ eps,
    float* __restrict__ out,
    unsigned* __restrict__ flags,   // [NC*CL*FLAG_STRIDE], zeroed by memset
    float* __restrict__ chunks)     // [NC][2][CL dest][CL src][BB][KS]
{
    __shared__ __align__(16) float hyL[BB][KS];
    __shared__ float lds_pad[13568];          // ~53 KB: cap residency at 2 WG/CU

    const int tid = threadIdx.x;
    const int w   = blockIdx.x;
    const int j   = w >> 5;   // slice id 0..7 (cluster mates share bid%8 -> XCD)
    const int c   = w & 31;   // cluster id 0..31

    lds_pad[tid] = 0.f;       // keep pad alive

    const int col = tid;      // partial-phase mapping: one thread per column
    const int ubb = tid >> 6; // update-phase mapping
    const int uoc = tid & 63;
    const bool upd = (ubb < BB);

    // --- register-resident weight slice: w_r[k] = h2h[(64j+k)*512 + col] ---
    float w_r[KS];
    #pragma unroll
    for (int k = 0; k < KS; ++k)
        w_r[k] = h2h[(size_t)(KS * j + k) * Hn + col];
    // Pin each element into a VGPR: value becomes opaque, cannot be
    // rematerialized as a per-step L2 reload.
    #pragma unroll
    for (int k = 0; k < KS; ++k)
        asm volatile("" : "+v"(w_r[k]));

    float hy = 0.f, hz = 0.f, g = 0.f, e = 0.f;
    size_t up_off = 0;
    if (upd) {
        g = gamma[KS * j + uoc];
        e = eps[KS * j + uoc];
        up_off = (size_t)(BB * c + ubb) * Tn * Hn + KS * j + uoc;
        hyL[ubb][uoc] = 0.f;
    }
    const int fbase = c * CL * FLAG_STRIDE;
    const int i_dest = col >> 6;
    const int oc_p   = col & 63;
    bool dead = false;
    __syncthreads();

    for (int t = 0; t < Tn; ++t) {
        const int par = t & 1;

        // prefetch u early (consumed after the exchange)
        float uval = 0.f;
        if (upd) uval = out[up_off + (size_t)t * Hn];

        // --- partial: own k-slice, all 512 cols, 4 batches ---
        float a0 = 0.f, a1 = 0.f, a2 = 0.f, a3 = 0.f;
        #pragma unroll
        for (int g4 = 0; g4 < KS / 4; ++g4) {
            const float4 h0 = *(const float4*)&hyL[0][4 * g4];
            const float4 h1 = *(const float4*)&hyL[1][4 * g4];
            const float4 h2 = *(const float4*)&hyL[2][4 * g4];
            const float4 h3 = *(const float4*)&hyL[3][4 * g4];
            a0 = fmaf(h0.x, w_r[4*g4+0], a0); a1 = fmaf(h1.x, w_r[4*g4+0], a1);
            a2 = fmaf(h2.x, w_r[4*g4+0], a2); a3 = fmaf(h3.x, w_r[4*g4+0], a3);
            a0 = fmaf(h0.y, w_r[4*g4+1], a0); a1 = fmaf(h1.y, w_r[4*g4+1], a1);
            a2 = fmaf(h2.y, w_r[4*g4+1], a2); a3 = fmaf(h3.y, w_r[4*g4+1], a3);
            a0 = fmaf(h0.z, w_r[4*g4+2], a0); a1 = fmaf(h1.z, w_r[4*g4+2], a1);
            a2 = fmaf(h2.z, w_r[4*g4+2], a2); a3 = fmaf(h3.z, w_r[4*g4+2], a3);
            a0 = fmaf(h0.w, w_r[4*g4+3], a0); a1 = fmaf(h1.w, w_r[4*g4+3], a1);
            a2 = fmaf(h2.w, w_r[4*g4+3], a2); a3 = fmaf(h3.w, w_r[4*g4+3], a3);
        }

        // --- scatter chunks to cluster mates (agent-scope atomic stores) ---
        {
            float* chp = chunks +
                ((((size_t)(c * 2 + par) * CL + i_dest) * CL + j) * BB) * KS + oc_p;
            __hip_atomic_store(&chp[0 * KS], a0, __ATOMIC_RELAXED, __HIP_MEMORY_SCOPE_AGENT);
            __hip_atomic_store(&chp[1 * KS], a1, __ATOMIC_RELAXED, __HIP_MEMORY_SCOPE_AGENT);
            __hip_atomic_store(&chp[2 * KS], a2, __ATOMIC_RELAXED, __HIP_MEMORY_SCOPE_AGENT);
            __hip_atomic_store(&chp[3 * KS], a3, __ATOMIC_RELAXED, __HIP_MEMORY_SCOPE_AGENT);
        }
        __syncthreads();  // B1: drains each wave's vmcnt; all chunk stores complete
        if (tid == 0)
            __hip_atomic_store(&flags[fbase + j * FLAG_STRIDE], (unsigned)(t + 1),
                               __ATOMIC_RELAXED, __HIP_MEMORY_SCOPE_AGENT);

        // --- all-lane poll by updater waves (no barrier needed after):
        // gather loads are control-dependent on the flag values, and issue
        // is in-order within a wave.
        if (upd && !dead) {
            const unsigned tgt = (unsigned)(t + 1);
            const unsigned* fp = &flags[fbase + (tid & (CL - 1)) * FLAG_STRIDE];
            int guard = 0;
            unsigned v;
            do {
                v = __hip_atomic_load(fp, __ATOMIC_RELAXED, __HIP_MEMORY_SCOPE_AGENT);
                if (++guard > (1 << 18)) { dead = true; break; }  // no-hang bailout
            } while (__any(v < tgt));
        }

        // --- gather 8 partials for own columns, update state ---
        if (upd) {
            const float* rdp = chunks +
                (((((size_t)(c * 2 + par) * CL + j) * CL) * BB) + ubb) * KS + uoc;
            float wsum = 0.f;
            #pragma unroll
            for (int p = 0; p < CL; ++p)
                wsum += __hip_atomic_load(&rdp[(size_t)p * BB * KS],
                                          __ATOMIC_RELAXED, __HIP_MEMORY_SCOPE_AGENT);
            hz += DT_C * (tanhf(uval + wsum) - g * hy - e * hz);
            hy += DT_C * hz;
            out[up_off + (size_t)t * Hn] = hy;
            hyL[ubb][uoc] = hy;
        }
        __syncthreads();  // B3: hyL visible for next step's partial
    }

    if (upd)
        out[(size_t)Bn * Tn * Hn + (size_t)(BB * c + ubb) * Hn + KS * j + uoc] = hy;
}

// ---------------------------------------------------------------------------
extern "C" void kernel_launch(void* const* d_in, const int* in_sizes, int n_in,
                              void* d_out, int out_size, void* d_ws, size_t ws_size,
                              hipStream_t stream) {
    const float* x     = (const float*)d_in[0];
    const float* x2h   = (const float*)d_in[1];
    const float* h2h   = (const float*)d_in[2];
    const float* bias  = (const float*)d_in[3];
    const float* gamma = (const float*)d_in[4];
    const float* eps   = (const float*)d_in[5];
    float* out = (float*)d_out;

    unsigned* flags = (unsigned*)d_ws;                       // 16 KB
    float*    chunks = (float*)((char*)d_ws + 16384);        // 4 MB

    // zero the step flags (chunks are flag-guarded, no init needed)
    hipMemsetAsync(d_ws, 0, NC * CL * FLAG_STRIDE * sizeof(unsigned), stream);

    ron_proj_kernel<<<(Bn * Tn) / ROWS_A, 512, 0, stream>>>(x, x2h, bias, out);
    ron_scan_kernel<<<NC * CL, 512, 0, stream>>>(h2h, gamma, eps, out, flags, chunks);
}

// Round 3
// 2872.589 us; speedup vs baseline: 1.3169x; 1.3169x over previous
//
#include <hip/hip_runtime.h>
#include <math.h>

#define DT_C 0.042f
#define Bn 128
#define Tn 1024
#define In 64
#define Hn 512

#define CL 8    // WGs per cluster (k-split factor)
#define NC 64   // clusters (2 per CU-pair domain; grid = NC*CL = 512 = 2 WG/CU)
#define BB 2    // batches per cluster
#define KS 64   // k-rows (and owned cols) per WG
#define FLAG_STRIDE 16  // uints (64 B) per flag

// ---------------------------------------------------------------------------
// Kernel A: u[b,t,h] = bias[h] + sum_i x[b,t,i] * x2h[i,h]  (in-place in d_out)
// ---------------------------------------------------------------------------
#define ROWS_A 256
__global__ __launch_bounds__(512) void ron_proj_kernel(
    const float* __restrict__ x, const float* __restrict__ x2h,
    const float* __restrict__ bias, float* __restrict__ u)
{
    __shared__ float xs[8 * In];
    const int h = threadIdx.x;
    const long row0 = (long)blockIdx.x * ROWS_A;

    float w[In];
    #pragma unroll
    for (int i = 0; i < In; ++i) w[i] = x2h[i * Hn + h];
    const float bh = bias[h];

    for (int r8 = 0; r8 < ROWS_A; r8 += 8) {
        __syncthreads();
        xs[h] = x[(row0 + r8) * In + h];
        __syncthreads();
        float acc[8];
        #pragma unroll
        for (int r = 0; r < 8; ++r) acc[r] = bh;
        #pragma unroll
        for (int i = 0; i < In; ++i) {
            #pragma unroll
            for (int r = 0; r < 8; ++r)
                acc[r] = fmaf(xs[r * In + i], w[i], acc[r]);
        }
        #pragma unroll
        for (int r = 0; r < 8; ++r)
            u[(row0 + r8 + r) * Hn + h] = acc[r];
    }
}

// ---------------------------------------------------------------------------
// Kernel B: k-split cluster scan. 512 WGs = 64 clusters x 8 WGs = 2 WG/CU.
// WG j of cluster c: h2h rows [64j,64j+64), owns hy/hz cols [64j,64j+64)
// for the cluster's 2 batches.
// The two WGs resident on each CU belong to DIFFERENT clusters (independent
// sync domains): one WG's compute fills the other's scatter-drain/poll/gather
// latency. R1 showed 1 WG/CU (23% occ) leaves the whole sync chain exposed.
//
// Sync protocol is RELAXED-only (R1: release/acquire cache maintenance = 2.7x):
//  - all inter-WG data (chunks, flags) moves via agent-scope ATOMIC ops;
//  - producer ordering: chunk stores -> __syncthreads (drains vmcnt) -> flag;
//  - consumer ordering: poll -> __syncthreads -> gather.
// Cross-step safety: flag(t+2) is stored after B1(t+2) > B3(t+1) > gather(t+1)
// of every mate, so parity buffers are never overwritten early.
//
// NOTE (R2 post-mortem): do NOT asm-pin w_r[] — the allocator spills it to
// scratch instead of keeping it resident (VGPR stays 56), which is slower
// than the L2 remat-reload it does by default.
// ---------------------------------------------------------------------------
__global__ __launch_bounds__(512, 4) void ron_scan_kernel(
    const float* __restrict__ h2h,
    const float* __restrict__ gamma,
    const float* __restrict__ eps,
    float* __restrict__ out,
    unsigned* __restrict__ flags,   // [NC*CL*FLAG_STRIDE], zeroed by memset
    float* __restrict__ chunks)     // [NC][2][CL dest][CL src][BB][KS]
{
    __shared__ __align__(16) float hyL[BB][KS];
    __shared__ float lds_pad[16256];          // 63.5 KB + hyL = 64 KB: cap 2 WG/CU

    const int tid = threadIdx.x;
    const int w   = blockIdx.x;
    const int j   = w >> 6;   // slice id 0..7 (mates share bid%8 -> same XCD)
    const int c   = w & 63;   // cluster id 0..63

    // keep the pad demonstrably live (prevent LDS-size DCE)
    lds_pad[tid] = 0.f;
    {
        float pv = lds_pad[tid ^ 1];
        asm volatile("" :: "v"(pv));
    }

    const int col = tid;      // partial-phase mapping: one thread per column
    const int ubb = tid >> 6; // update-phase mapping
    const int uoc = tid & 63;
    const bool upd = (ubb < BB);

    // --- weight slice: w_r[k] = h2h[(64j+k)*512 + col] (compiler remats from L2) ---
    float w_r[KS];
    #pragma unroll
    for (int k = 0; k < KS; ++k)
        w_r[k] = h2h[(size_t)(KS * j + k) * Hn + col];

    float hy = 0.f, hz = 0.f, g = 0.f, e = 0.f;
    size_t up_off = 0;
    if (upd) {
        g = gamma[KS * j + uoc];
        e = eps[KS * j + uoc];
        up_off = (size_t)(BB * c + ubb) * Tn * Hn + KS * j + uoc;
        hyL[ubb][uoc] = 0.f;
    }
    const int fbase = c * CL * FLAG_STRIDE;
    const int i_dest = col >> 6;
    const int oc_p   = col & 63;
    bool dead = false;
    __syncthreads();

    for (int t = 0; t < Tn; ++t) {
        const int par = t & 1;

        // prefetch u early (consumed after the exchange)
        float uval = 0.f;
        if (upd) uval = out[up_off + (size_t)t * Hn];

        // --- partial: own k-slice, all 512 cols, 2 batches ---
        float a0 = 0.f, a1 = 0.f;
        #pragma unroll
        for (int g4 = 0; g4 < KS / 4; ++g4) {
            const float4 h0 = *(const float4*)&hyL[0][4 * g4];
            const float4 h1 = *(const float4*)&hyL[1][4 * g4];
            a0 = fmaf(h0.x, w_r[4*g4+0], a0); a1 = fmaf(h1.x, w_r[4*g4+0], a1);
            a0 = fmaf(h0.y, w_r[4*g4+1], a0); a1 = fmaf(h1.y, w_r[4*g4+1], a1);
            a0 = fmaf(h0.z, w_r[4*g4+2], a0); a1 = fmaf(h1.z, w_r[4*g4+2], a1);
            a0 = fmaf(h0.w, w_r[4*g4+3], a0); a1 = fmaf(h1.w, w_r[4*g4+3], a1);
        }

        // --- scatter chunks to cluster mates (agent-scope atomic stores) ---
        {
            float* chp = chunks +
                ((((size_t)(c * 2 + par) * CL + i_dest) * CL + j) * BB) * KS + oc_p;
            __hip_atomic_store(&chp[0 * KS], a0, __ATOMIC_RELAXED, __HIP_MEMORY_SCOPE_AGENT);
            __hip_atomic_store(&chp[1 * KS], a1, __ATOMIC_RELAXED, __HIP_MEMORY_SCOPE_AGENT);
        }
        __syncthreads();  // B1: drains each wave's vmcnt; all chunk stores complete
        if (tid == 0)
            __hip_atomic_store(&flags[fbase + j * FLAG_STRIDE], (unsigned)(t + 1),
                               __ATOMIC_RELAXED, __HIP_MEMORY_SCOPE_AGENT);
        if (tid < CL && !dead) {
            const unsigned tgt = (unsigned)(t + 1);
            int guard = 0;
            while (__hip_atomic_load(&flags[fbase + tid * FLAG_STRIDE],
                                     __ATOMIC_RELAXED, __HIP_MEMORY_SCOPE_AGENT) < tgt) {
                if (++guard > (1 << 18)) { dead = true; break; }  // no-hang bailout
            }
        }
        __syncthreads();  // B2: orders poll-before-gather for all threads

        // --- gather 8 partials for own columns, update state ---
        if (upd) {
            const float* rdp = chunks +
                (((((size_t)(c * 2 + par) * CL + j) * CL) * BB) + ubb) * KS + uoc;
            float wsum = 0.f;
            #pragma unroll
            for (int p = 0; p < CL; ++p)
                wsum += __hip_atomic_load(&rdp[(size_t)p * BB * KS],
                                          __ATOMIC_RELAXED, __HIP_MEMORY_SCOPE_AGENT);
            hz += DT_C * (tanhf(uval + wsum) - g * hy - e * hz);
            hy += DT_C * hz;
            out[up_off + (size_t)t * Hn] = hy;
            hyL[ubb][uoc] = hy;
        }
        __syncthreads();  // B3: hyL visible for next step's partial
    }

    if (upd)
        out[(size_t)Bn * Tn * Hn + (size_t)(BB * c + ubb) * Hn + KS * j + uoc] = hy;
}

// ---------------------------------------------------------------------------
extern "C" void kernel_launch(void* const* d_in, const int* in_sizes, int n_in,
                              void* d_out, int out_size, void* d_ws, size_t ws_size,
                              hipStream_t stream) {
    const float* x     = (const float*)d_in[0];
    const float* x2h   = (const float*)d_in[1];
    const float* h2h   = (const float*)d_in[2];
    const float* bias  = (const float*)d_in[3];
    const float* gamma = (const float*)d_in[4];
    const float* eps   = (const float*)d_in[5];
    float* out = (float*)d_out;

    unsigned* flags = (unsigned*)d_ws;                        // 32 KB
    float*    chunks = (float*)((char*)d_ws + 32768);         // 4 MB

    // zero the step flags (chunks are flag-guarded, no init needed)
    hipMemsetAsync(d_ws, 0, NC * CL * FLAG_STRIDE * sizeof(unsigned), stream);

    ron_proj_kernel<<<(Bn * Tn) / ROWS_A, 512, 0, stream>>>(x, x2h, bias, out);
    ron_scan_kernel<<<NC * CL, 512, 0, stream>>>(h2h, gamma, eps, out, flags, chunks);
}